// Round 9
// baseline (4410.204 us; speedup 1.0000x reference)
//
#include <hip/hip_runtime.h>
#include <stdint.h>

typedef _Float16 f16;
typedef __attribute__((ext_vector_type(8))) _Float16 f16x8;
typedef __attribute__((ext_vector_type(4))) float f32x4;

#define BD 64      // state dim D
#define HW 512     // hidden width W
#define TT 16      // time points T
#define BR 16      // batch rows per group
#define NTHREADS 512
#define NTEAM 16   // teams of 4 CUs; each team serves 2 batch groups
#define NCU 4

// lgkm-only barrier: LDS producer->consumer, no vmcnt drain
#define LBAR() asm volatile("s_waitcnt lgkmcnt(0)\n\ts_barrier" ::: "memory")
#define VM_DRAIN() asm volatile("s_waitcnt vmcnt(0)" ::: "memory")

// Tsit5 coefficients
constexpr float cA21 = 0.161f;
constexpr float cA31 = -0.008480655492356989f, cA32 = 0.335480655492357f;
constexpr float cA41 = 2.8971530571054935f, cA42 = -6.359448489975075f, cA43 = 4.3622954328695815f;
constexpr float cA51 = 5.325864828439257f, cA52 = -11.748883564062828f, cA53 = 7.4955393428898365f, cA54 = -0.09249506636175525f;
constexpr float cA61 = 5.86145544294642f, cA62 = -12.92096931784711f, cA63 = 8.159367898576159f, cA64 = -0.071584973281401f, cA65 = -0.028269050394068383f;
constexpr float cB1 = 0.09646076681806523f, cB2 = 0.01f, cB3 = 0.4798896504144996f;
constexpr float cB4 = 1.379008574103742f, cB5 = -3.290069515436081f, cB6 = 2.324710524099774f;

__device__ __forceinline__ float softplus_f(float x) {
  return fmaxf(x, 0.0f) + __logf(1.0f + __expf(-fabsf(x)));
}

// convert W0 [512,64], W1 [512,512], W2 [64,512] (row-major f32) to fp16 in ws
__global__ void cvt_kernel(const float* __restrict__ w0,
                           const float* __restrict__ w1,
                           const float* __restrict__ w2,
                           f16* __restrict__ wsh) {
  int i = blockIdx.x * 512 + threadIdx.x;
  if (i < 32768) wsh[i] = (f16)w0[i];
  else if (i < 294912) wsh[i] = (f16)w1[i - 32768];
  else if (i < 327680) wsh[i] = (f16)w2[i - 294912];
}

__global__ __launch_bounds__(NTHREADS, 2)
void ode_kernel(const float* __restrict__ ts,
                const float* __restrict__ y0,
                const float* __restrict__ b0,
                const float* __restrict__ b1,
                const float* __restrict__ b2,
                const f16* __restrict__ W0h,
                const f16* __restrict__ W1h,
                const f16* __restrict__ W2h,
                float* __restrict__ out,
                float* partials,
                unsigned int* flags) {
  // resident swizzled W1 slice: 128 rows x 512 cols fp16 = 128 KB (shared by both groups)
  __shared__ __align__(16) f16 w1s[128 * HW];
  __shared__ __align__(16) f16 h0buf[BR][HW + 8];   // time-shared X/Y
  __shared__ __align__(16) f16 h1buf[BR][128 + 8];  // time-shared X/Y
  __shared__ __align__(16) f16 atile[2][BR][BD + 8];
  __shared__ float hsteps[TT - 1];

  const int tid  = threadIdx.x;
  const int wave = tid >> 6;
  const int lane = tid & 63;
  const int m = lane & 15;   // MFMA col index
  const int g = lane >> 4;   // lane group 0..3
  const int b = blockIdx.x;
  const int team = b & 15;   // teammates {team, team+16, +32, +48}
  const int cuj  = b >> 4;   // which quarter of W1/h1/K this CU owns
  const int gX = team * 2, gY = gX + 1;   // two batch groups served
  const int cbase = wave * 64;  // layer-1 output-col base
  const int ntile = wave & 3;   // layer-3 output col tile (waves 4-7 duplicate)
  const int r0 = tid >> 6, d = tid & 63;  // per-thread output elems (r0,d),(r0+8,d)

  // ---- loop-invariant registers ----
  f16x8 w0r[2][4];
#pragma unroll
  for (int kt = 0; kt < 2; ++kt)
#pragma unroll
    for (int nt = 0; nt < 4; ++nt)
      w0r[kt][nt] = *(const f16x8*)&W0h[(cbase + nt * 16 + m) * BD + kt * 32 + g * 8];
  f16x8 w2r[4];  // W2 K-slice [cuj*128, +128) for out tile ntile
#pragma unroll
  for (int kt = 0; kt < 4; ++kt)
    w2r[kt] = *(const f16x8*)&W2h[(ntile * 16 + m) * HW + cuj * 128 + kt * 32 + g * 8];
  float bias0[4];
#pragma unroll
  for (int nt = 0; nt < 4; ++nt) bias0[nt] = b0[cbase + nt * 16 + m];
  const float bias1 = b1[cuj * 128 + wave * 16 + m];
  const float b2d = b2[d];

  // ---- y state in registers (both groups) ----
  float yx0 = y0[(gX * BR + r0) * BD + d];
  float yx1 = y0[(gX * BR + r0 + 8) * BD + d];
  float yy0 = y0[(gY * BR + r0) * BD + d];
  float yy1 = y0[(gY * BR + r0 + 8) * BD + d];
  atile[0][r0][d] = (f16)yx0;
  atile[0][r0 + 8][d] = (f16)yx1;
  atile[1][r0][d] = (f16)yy0;
  atile[1][r0 + 8][d] = (f16)yy1;
  if (cuj == 0) {
    out[(gX * BR + r0) * (TT * BD) + d] = yx0;
    out[(gX * BR + r0 + 8) * (TT * BD) + d] = yx1;
    out[(gY * BR + r0) * (TT * BD) + d] = yy0;
    out[(gY * BR + r0 + 8) * (TT * BD) + d] = yy1;
  }
  if (tid < TT - 1) hsteps[tid] = (ts[tid + 1] - ts[tid]) * 0.25f;

  // ---- stage resident W1 slice into LDS, XOR-swizzled: byte ^= (row&7)<<4 ----
  for (int idx = tid; idx < 128 * 64; idx += NTHREADS) {
    const int row = idx >> 6, ch = idx & 63;           // ch = 16B chunk (8 f16)
    const f16x8 v = *(const f16x8*)&W1h[(size_t)(cuj * 128 + row) * HW + ch * 8];
    *(f16x8*)((char*)w1s + row * 1024 + ((ch * 16) ^ ((row & 7) << 4))) = v;
  }
  LBAR();

  const int brow = wave * 16 + m;            // this lane's W1-slice row (local)
  const char* const w1base = (const char*)w1s + brow * 1024;
  const int rsw = (brow & 7) << 4;           // read-side swizzle

  unsigned int fstep = 0;
  unsigned int* const flagX = &flags[gX * 32];   // one 128B line per group (R4 layout)
  unsigned int* const flagY = &flags[gY * 32];

  // one MLP eval for group gi at stage st: compute + store partial + SIGNAL (no wait)
  auto feval = [&](int gi, int st) {
    // layer 1: full h0 (replicated), W0 in regs
    {
      f32x4 acc[4] = {{0,0,0,0},{0,0,0,0},{0,0,0,0},{0,0,0,0}};
#pragma unroll
      for (int kt = 0; kt < 2; ++kt) {
        const f16x8 a = *(const f16x8*)&atile[gi][m][kt * 32 + g * 8];
#pragma unroll
        for (int nt = 0; nt < 4; ++nt)
          acc[nt] = __builtin_amdgcn_mfma_f32_16x16x32_f16(a, w0r[kt][nt], acc[nt], 0, 0, 0);
      }
#pragma unroll
      for (int nt = 0; nt < 4; ++nt) {
        const int n = cbase + nt * 16 + m;
#pragma unroll
        for (int j = 0; j < 4; ++j)
          h0buf[g * 4 + j][n] = (f16)softplus_f(acc[nt][j] + bias0[nt]);
      }
    }
    LBAR();
    // layer 2: 16 local h1 cols per wave, W1 from resident swizzled LDS
    {
      f32x4 acc1 = {0, 0, 0, 0};
#pragma unroll
      for (int kt = 0; kt < 16; ++kt) {
        const f16x8 a = *(const f16x8*)&h0buf[m][kt * 32 + g * 8];
        const f16x8 bb = *(const f16x8*)(w1base + ((kt * 64 + g * 16) ^ rsw));
        acc1 = __builtin_amdgcn_mfma_f32_16x16x32_f16(a, bb, acc1, 0, 0, 0);
      }
#pragma unroll
      for (int j = 0; j < 4; ++j)
        h1buf[g * 4 + j][wave * 16 + m] = (f16)softplus_f(acc1[j] + bias1);
    }
    LBAR();
    // layer 3: split-K partial (local K=128)
    f32x4 acc3 = {0, 0, 0, 0};
#pragma unroll
    for (int kt = 0; kt < 4; ++kt) {
      const f16x8 a = *(const f16x8*)&h1buf[m][kt * 32 + g * 8];
      acc3 = __builtin_amdgcn_mfma_f32_16x16x32_f16(a, w2r[kt], acc3, 0, 0, 0);
    }
    const int grp = gi ? gY : gX;
    float* const pb = partials + ((size_t)(grp * 6 + st) * 4 + cuj) * 1024;
    if (wave < 4) {
#pragma unroll
      for (int j = 0; j < 4; ++j)
        __hip_atomic_store(&pb[(g * 4 + j) * 64 + ntile * 16 + m], acc3[j],
                           __ATOMIC_RELAXED, __HIP_MEMORY_SCOPE_AGENT);
    }
    VM_DRAIN();          // own partial stores at coherence point
    LBAR();              // all waves of this block drained
    if (tid == 0)
      __hip_atomic_fetch_add(gi ? flagY : flagX, 1u,
                             __ATOMIC_RELEASE, __HIP_MEMORY_SCOPE_AGENT);
  };

  // wait for the 4 team partials of (gi, st), then gather into KA/KB
  auto waitgather = [&](int gi, int st, float& KA, float& KB) {
    const unsigned int target = 4u * fstep;
    unsigned int* const fp = gi ? flagY : flagX;
    if (tid == 0) {
      unsigned int f;
      do {
        f = __hip_atomic_load(fp, __ATOMIC_RELAXED, __HIP_MEMORY_SCOPE_AGENT);
        if (f < target) __builtin_amdgcn_s_sleep(1);
      } while (f < target);
    }
    __syncthreads();
    __builtin_amdgcn_fence(__ATOMIC_ACQUIRE, "agent");
    const int grp = gi ? gY : gX;
    const float* const q = partials + (size_t)(grp * 6 + st) * 4096;
    float s0 = 0.f, s1 = 0.f;
#pragma unroll
    for (int c = 0; c < 4; ++c) {
      s0 += __hip_atomic_load(q + c * 1024 + tid,       __ATOMIC_RELAXED, __HIP_MEMORY_SCOPE_AGENT);
      s1 += __hip_atomic_load(q + c * 1024 + tid + 512, __ATOMIC_RELAXED, __HIP_MEMORY_SCOPE_AGENT);
    }
    KA = s0 + b2d;
    KB = s1 + b2d;
  };

  float k1x0,k1x1,k2x0,k2x1,k3x0,k3x1,k4x0,k4x1,k5x0,k5x1,k6x0,k6x1;
  float k1y0,k1y1,k2y0,k2y1,k3y0,k3y1,k4y0,k4y1,k5y0,k5y1,k6y0,k6y1;

// one Tsit5 stage for both groups: compute X, compute Y (X's sync hides under Y),
// then gather+combine X, gather+combine Y.
#define STAGE(ST, KXA,KXB,KYA,KYB, EX0,EX1,EY0,EY1)                  \
  ++fstep;                                                           \
  feval(0, ST); feval(1, ST);                                        \
  waitgather(0, ST, KXA, KXB);                                       \
  atile[0][r0][d] = (f16)(EX0); atile[0][r0 + 8][d] = (f16)(EX1);    \
  waitgather(1, ST, KYA, KYB);                                       \
  atile[1][r0][d] = (f16)(EY0); atile[1][r0 + 8][d] = (f16)(EY1);    \
  LBAR();

  for (int t = 0; t < TT - 1; ++t) {
    const float h = hsteps[t];
    for (int s = 0; s < 4; ++s) {
      STAGE(0, k1x0,k1x1,k1y0,k1y1,
            yx0 + h * (cA21 * k1x0), yx1 + h * (cA21 * k1x1),
            yy0 + h * (cA21 * k1y0), yy1 + h * (cA21 * k1y1))
      STAGE(1, k2x0,k2x1,k2y0,k2y1,
            yx0 + h * (cA31 * k1x0 + cA32 * k2x0), yx1 + h * (cA31 * k1x1 + cA32 * k2x1),
            yy0 + h * (cA31 * k1y0 + cA32 * k2y0), yy1 + h * (cA31 * k1y1 + cA32 * k2y1))
      STAGE(2, k3x0,k3x1,k3y0,k3y1,
            yx0 + h * (cA41 * k1x0 + cA42 * k2x0 + cA43 * k3x0),
            yx1 + h * (cA41 * k1x1 + cA42 * k2x1 + cA43 * k3x1),
            yy0 + h * (cA41 * k1y0 + cA42 * k2y0 + cA43 * k3y0),
            yy1 + h * (cA41 * k1y1 + cA42 * k2y1 + cA43 * k3y1))
      STAGE(3, k4x0,k4x1,k4y0,k4y1,
            yx0 + h * (cA51 * k1x0 + cA52 * k2x0 + cA53 * k3x0 + cA54 * k4x0),
            yx1 + h * (cA51 * k1x1 + cA52 * k2x1 + cA53 * k3x1 + cA54 * k4x1),
            yy0 + h * (cA51 * k1y0 + cA52 * k2y0 + cA53 * k3y0 + cA54 * k4y0),
            yy1 + h * (cA51 * k1y1 + cA52 * k2y1 + cA53 * k3y1 + cA54 * k4y1))
      STAGE(4, k5x0,k5x1,k5y0,k5y1,
            yx0 + h * (cA61 * k1x0 + cA62 * k2x0 + cA63 * k3x0 + cA64 * k4x0 + cA65 * k5x0),
            yx1 + h * (cA61 * k1x1 + cA62 * k2x1 + cA63 * k3x1 + cA64 * k4x1 + cA65 * k5x1),
            yy0 + h * (cA61 * k1y0 + cA62 * k2y0 + cA63 * k3y0 + cA64 * k4y0 + cA65 * k5y0),
            yy1 + h * (cA61 * k1y1 + cA62 * k2y1 + cA63 * k3y1 + cA64 * k4y1 + cA65 * k5y1))
      // stage 6: y-update, atile = y_new
      ++fstep;
      feval(0, 5); feval(1, 5);
      waitgather(0, 5, k6x0, k6x1);
      yx0 += h * (cB1 * k1x0 + cB2 * k2x0 + cB3 * k3x0 + cB4 * k4x0 + cB5 * k5x0 + cB6 * k6x0);
      yx1 += h * (cB1 * k1x1 + cB2 * k2x1 + cB3 * k3x1 + cB4 * k4x1 + cB5 * k5x1 + cB6 * k6x1);
      atile[0][r0][d] = (f16)yx0;
      atile[0][r0 + 8][d] = (f16)yx1;
      waitgather(1, 5, k6y0, k6y1);
      yy0 += h * (cB1 * k1y0 + cB2 * k2y0 + cB3 * k3y0 + cB4 * k4y0 + cB5 * k5y0 + cB6 * k6y0);
      yy1 += h * (cB1 * k1y1 + cB2 * k2y1 + cB3 * k3y1 + cB4 * k4y1 + cB5 * k5y1 + cB6 * k6y1);
      atile[1][r0][d] = (f16)yy0;
      atile[1][r0 + 8][d] = (f16)yy1;
      LBAR();
    }
    if (cuj == 0) {
      out[(gX * BR + r0) * (TT * BD) + (t + 1) * BD + d] = yx0;
      out[(gX * BR + r0 + 8) * (TT * BD) + (t + 1) * BD + d] = yx1;
      out[(gY * BR + r0) * (TT * BD) + (t + 1) * BD + d] = yy0;
      out[(gY * BR + r0 + 8) * (TT * BD) + (t + 1) * BD + d] = yy1;
    }
  }
#undef STAGE
}

extern "C" void kernel_launch(void* const* d_in, const int* in_sizes, int n_in,
                              void* d_out, int out_size, void* d_ws, size_t ws_size,
                              hipStream_t stream) {
  const float* ts = (const float*)d_in[0];
  const float* y0 = (const float*)d_in[1];
  const float* W0 = (const float*)d_in[2];
  const float* b0 = (const float*)d_in[3];
  const float* W1 = (const float*)d_in[4];
  const float* b1 = (const float*)d_in[5];
  const float* W2 = (const float*)d_in[6];
  const float* b2 = (const float*)d_in[7];
  // ws: [0,640K) fp16 weights | 655360: flags (8KB) | 671744: k-partials (3MB)
  f16* wsh = (f16*)d_ws;
  unsigned int* flags = (unsigned int*)((char*)d_ws + 655360);
  float* partials = (float*)((char*)d_ws + 671744);

  cvt_kernel<<<640, 512, 0, stream>>>(W0, W1, W2, wsh);
  hipMemsetAsync(flags, 0, 8192, stream);
  ode_kernel<<<NTEAM * NCU, NTHREADS, 0, stream>>>(ts, y0, b0, b1, b2,
                                                   wsh, wsh + 32768, wsh + 294912,
                                                   (float*)d_out, partials, flags);
}

// Round 10
// 3581.054 us; speedup vs baseline: 1.2315x; 1.2315x over previous
//
#include <hip/hip_runtime.h>
#include <stdint.h>

typedef _Float16 f16;
typedef __attribute__((ext_vector_type(8))) _Float16 f16x8;
typedef __attribute__((ext_vector_type(4))) float f32x4;

#define BD 64      // state dim D
#define HW 512     // hidden width W
#define TT 16      // time points T
#define BR 16      // batch rows per group
#define NTHREADS 512
#define NGRP 32    // batch groups (512/16)
#define NCU 4      // CUs per group (W1 split 4 ways, 128 KB LDS-resident each)

// lgkm-only barrier: LDS producer->consumer, no vmcnt drain
#define LBAR() asm volatile("s_waitcnt lgkmcnt(0)\n\ts_barrier" ::: "memory")
#define VM_DRAIN() asm volatile("s_waitcnt vmcnt(0)" ::: "memory")

// Tsit5 coefficients
constexpr float cA21 = 0.161f;
constexpr float cA31 = -0.008480655492356989f, cA32 = 0.335480655492357f;
constexpr float cA41 = 2.8971530571054935f, cA42 = -6.359448489975075f, cA43 = 4.3622954328695815f;
constexpr float cA51 = 5.325864828439257f, cA52 = -11.748883564062828f, cA53 = 7.4955393428898365f, cA54 = -0.09249506636175525f;
constexpr float cA61 = 5.86145544294642f, cA62 = -12.92096931784711f, cA63 = 8.159367898576159f, cA64 = -0.071584973281401f, cA65 = -0.028269050394068383f;
constexpr float cB1 = 0.09646076681806523f, cB2 = 0.01f, cB3 = 0.4798896504144996f;
constexpr float cB4 = 1.379008574103742f, cB5 = -3.290069515436081f, cB6 = 2.324710524099774f;

__device__ __forceinline__ float softplus_f(float x) {
  return fmaxf(x, 0.0f) + __logf(1.0f + __expf(-fabsf(x)));
}

// convert W0 [512,64], W1 [512,512], W2 [64,512] (row-major f32) to fp16 in ws
__global__ void cvt_kernel(const float* __restrict__ w0,
                           const float* __restrict__ w1,
                           const float* __restrict__ w2,
                           f16* __restrict__ wsh) {
  int i = blockIdx.x * 512 + threadIdx.x;
  if (i < 32768) wsh[i] = (f16)w0[i];
  else if (i < 294912) wsh[i] = (f16)w1[i - 32768];
  else if (i < 327680) wsh[i] = (f16)w2[i - 294912];
}

__global__ __launch_bounds__(NTHREADS)
void ode_kernel(const float* __restrict__ ts,
                const float* __restrict__ y0,
                const float* __restrict__ b0,
                const float* __restrict__ b1,
                const float* __restrict__ b2,
                const f16* __restrict__ W0h,
                const f16* __restrict__ W1h,
                const f16* __restrict__ W2h,
                float* __restrict__ out,
                float* partials,
                unsigned int* flags) {
  // resident swizzled W1 slice: 128 rows x 512 cols fp16 = 131072 B
  __shared__ __align__(16) f16 w1s[128 * HW];
  __shared__ __align__(16) f16 h0buf[BR][HW + 8];
  __shared__ __align__(16) f16 h1buf[BR][128 + 8];
  __shared__ __align__(16) f16 atile[BR][BD + 8];
  __shared__ float hsteps[TT - 1];

  const int tid  = threadIdx.x;
  const int wave = tid >> 6;
  const int lane = tid & 63;
  const int m = lane & 15;   // MFMA col index
  const int g = lane >> 4;   // lane group 0..3
  const int b = blockIdx.x;
  const int grp = b & 31;    // batch group; teammates {grp, grp+32, +64, +96}
  const int cuj = b >> 5;    // which quarter of W1/h1/K this CU owns
  const int row0 = grp * BR;
  const int cbase = wave * 64;  // layer-1 output-col base
  const int ntile = wave & 3;   // layer-3 output col tile (waves 0-3 only)
  const int r0 = tid >> 6, d = tid & 63;   // per-thread output elems (r0,d),(r0+8,d)

  // ---- loop-invariant registers ----
  f16x8 w0r[2][4];
#pragma unroll
  for (int kt = 0; kt < 2; ++kt)
#pragma unroll
    for (int nt = 0; nt < 4; ++nt)
      w0r[kt][nt] = *(const f16x8*)&W0h[(cbase + nt * 16 + m) * BD + kt * 32 + g * 8];
  f16x8 w2r[4];  // W2 K-slice [cuj*128, +128) for out tile ntile
#pragma unroll
  for (int kt = 0; kt < 4; ++kt)
    w2r[kt] = *(const f16x8*)&W2h[(ntile * 16 + m) * HW + cuj * 128 + kt * 32 + g * 8];
  float bias0[4];
#pragma unroll
  for (int nt = 0; nt < 4; ++nt) bias0[nt] = b0[cbase + nt * 16 + m];
  // L2 consolidated onto waves 0-1 (4 out-tiles each); per-tile bias
  float bias1v[4] = {0.f, 0.f, 0.f, 0.f};
  if (wave < 2) {
#pragma unroll
    for (int tt = 0; tt < 4; ++tt)
      bias1v[tt] = b1[cuj * 128 + (wave * 4 + tt) * 16 + m];
  }
  const float b2d = b2[d];

  // ---- y state in registers ----
  float yreg0 = y0[(row0 + r0) * BD + d];
  float yreg1 = y0[(row0 + r0 + 8) * BD + d];
  atile[r0][d] = (f16)yreg0;
  atile[r0 + 8][d] = (f16)yreg1;
  if (cuj == 0) {
    out[(row0 + r0) * (TT * BD) + d] = yreg0;
    out[(row0 + r0 + 8) * (TT * BD) + d] = yreg1;
  }
  if (tid < TT - 1) hsteps[tid] = (ts[tid + 1] - ts[tid]) * 0.25f;

  // ---- stage resident W1 slice into LDS, XOR-swizzled: byte ^= (row&7)<<4 ----
  for (int idx = tid; idx < 128 * 64; idx += NTHREADS) {
    const int row = idx >> 6, ch = idx & 63;           // ch = 16B chunk (8 f16)
    const f16x8 v = *(const f16x8*)&W1h[(size_t)(cuj * 128 + row) * HW + ch * 8];
    *(f16x8*)((char*)w1s + row * 1024 + ((ch * 16) ^ ((row & 7) << 4))) = v;
  }
  LBAR();

  const int rsw = (m & 7) << 4;   // read-side swizzle ((gt*16+m)&7 == m&7)

  int fstep = 0;
  unsigned int* const flagp = &flags[grp * 32];   // one line per group (R4 layout)

  // one MLP eval of f(atile); k distributed into (KA,KB) on every CU
  auto feval = [&](int st, float& KA, float& KB) {
    // ---- layer 1: full h0 (replicated output-split across 8 waves), W0 in regs
    {
      f32x4 acc[4] = {{0,0,0,0},{0,0,0,0},{0,0,0,0},{0,0,0,0}};
#pragma unroll
      for (int kt = 0; kt < 2; ++kt) {
        const f16x8 a = *(const f16x8*)&atile[m][kt * 32 + g * 8];
#pragma unroll
        for (int nt = 0; nt < 4; ++nt)
          acc[nt] = __builtin_amdgcn_mfma_f32_16x16x32_f16(a, w0r[kt][nt], acc[nt], 0, 0, 0);
      }
#pragma unroll
      for (int nt = 0; nt < 4; ++nt) {
        const int n = cbase + nt * 16 + m;
#pragma unroll
        for (int j = 0; j < 4; ++j)
          h0buf[g * 4 + j][n] = (f16)softplus_f(acc[nt][j] + bias0[nt]);
      }
    }
    LBAR();
    // ---- layer 2 (consolidated): waves 0-1 compute 64 cols each (4 out-tiles),
    // ONE shared A-read per kt (was 8x redundant across waves)
    if (wave < 2) {
      f32x4 acc[4] = {{0,0,0,0},{0,0,0,0},{0,0,0,0},{0,0,0,0}};
#pragma unroll
      for (int kt = 0; kt < 16; ++kt) {
        const f16x8 a = *(const f16x8*)&h0buf[m][kt * 32 + g * 8];
#pragma unroll
        for (int tt = 0; tt < 4; ++tt) {
          const char* wb = (const char*)w1s + ((wave * 4 + tt) * 16 + m) * 1024;
          const f16x8 bb = *(const f16x8*)(wb + ((kt * 64 + g * 16) ^ rsw));
          acc[tt] = __builtin_amdgcn_mfma_f32_16x16x32_f16(a, bb, acc[tt], 0, 0, 0);
        }
      }
#pragma unroll
      for (int tt = 0; tt < 4; ++tt) {
#pragma unroll
        for (int j = 0; j < 4; ++j)
          h1buf[g * 4 + j][(wave * 4 + tt) * 16 + m] =
              (f16)softplus_f(acc[tt][j] + bias1v[tt]);
      }
    }
    LBAR();
    // ---- layer 3: split-K partial (local K=128); waves 0-3 only (no duplication)
    if (wave < 4) {
      f32x4 acc3 = {0, 0, 0, 0};
#pragma unroll
      for (int kt = 0; kt < 4; ++kt) {
        const f16x8 a = *(const f16x8*)&h1buf[m][kt * 32 + g * 8];
        acc3 = __builtin_amdgcn_mfma_f32_16x16x32_f16(a, w2r[kt], acc3, 0, 0, 0);
      }
      float* const pb = partials + ((size_t)(grp * 6 + st) * 4 + cuj) * 1024;
#pragma unroll
      for (int j = 0; j < 4; ++j)
        __hip_atomic_store(&pb[(g * 4 + j) * 64 + ntile * 16 + m], acc3[j],
                           __ATOMIC_RELAXED, __HIP_MEMORY_SCOPE_AGENT);
    }
    VM_DRAIN();          // own partial stores at coherence point
    LBAR();              // all waves of this block drained
    ++fstep;
    const unsigned int target = 4u * (unsigned int)fstep;
    if (tid == 0) {
      __hip_atomic_fetch_add(flagp, 1u, __ATOMIC_RELEASE, __HIP_MEMORY_SCOPE_AGENT);
      unsigned int f;
      do {
        f = __hip_atomic_load(flagp, __ATOMIC_ACQUIRE, __HIP_MEMORY_SCOPE_AGENT);
      } while (f < target);
    }
    __syncthreads();
    __builtin_amdgcn_fence(__ATOMIC_ACQUIRE, "agent");
    // gather: k[tid], k[tid+512] = sum of 4 CU partials (+ bias); idx=tid (coalesced)
    const float* const q = partials + (size_t)(grp * 6 + st) * 4096;
    float s0 = 0.f, s1 = 0.f;
#pragma unroll
    for (int c = 0; c < 4; ++c) {
      s0 += __hip_atomic_load(q + c * 1024 + tid,       __ATOMIC_RELAXED, __HIP_MEMORY_SCOPE_AGENT);
      s1 += __hip_atomic_load(q + c * 1024 + tid + 512, __ATOMIC_RELAXED, __HIP_MEMORY_SCOPE_AGENT);
    }
    KA = s0 + b2d;
    KB = s1 + b2d;
  };

  float k1a, k1b, k2a, k2b, k3a, k3b, k4a, k4b, k5a, k5b, k6a, k6b;

#define PUT_ATILE(E0, E1) \
  atile[r0][d] = (f16)(E0); atile[r0 + 8][d] = (f16)(E1); LBAR();

  for (int t = 0; t < TT - 1; ++t) {
    const float h = hsteps[t];
    for (int s = 0; s < 4; ++s) {
      feval(0, k1a, k1b);
      PUT_ATILE(yreg0 + h * (cA21 * k1a), yreg1 + h * (cA21 * k1b))
      feval(1, k2a, k2b);
      PUT_ATILE(yreg0 + h * (cA31 * k1a + cA32 * k2a),
                yreg1 + h * (cA31 * k1b + cA32 * k2b))
      feval(2, k3a, k3b);
      PUT_ATILE(yreg0 + h * (cA41 * k1a + cA42 * k2a + cA43 * k3a),
                yreg1 + h * (cA41 * k1b + cA42 * k2b + cA43 * k3b))
      feval(3, k4a, k4b);
      PUT_ATILE(yreg0 + h * (cA51 * k1a + cA52 * k2a + cA53 * k3a + cA54 * k4a),
                yreg1 + h * (cA51 * k1b + cA52 * k2b + cA53 * k3b + cA54 * k4b))
      feval(4, k5a, k5b);
      PUT_ATILE(yreg0 + h * (cA61 * k1a + cA62 * k2a + cA63 * k3a + cA64 * k4a + cA65 * k5a),
                yreg1 + h * (cA61 * k1b + cA62 * k2b + cA63 * k3b + cA64 * k4b + cA65 * k5b))
      feval(5, k6a, k6b);
      yreg0 += h * (cB1 * k1a + cB2 * k2a + cB3 * k3a + cB4 * k4a + cB5 * k5a + cB6 * k6a);
      yreg1 += h * (cB1 * k1b + cB2 * k2b + cB3 * k3b + cB4 * k4b + cB5 * k5b + cB6 * k6b);
      PUT_ATILE(yreg0, yreg1)
    }
    if (cuj == 0) {
      out[(row0 + r0) * (TT * BD) + (t + 1) * BD + d] = yreg0;
      out[(row0 + r0 + 8) * (TT * BD) + (t + 1) * BD + d] = yreg1;
    }
  }
#undef PUT_ATILE
}

extern "C" void kernel_launch(void* const* d_in, const int* in_sizes, int n_in,
                              void* d_out, int out_size, void* d_ws, size_t ws_size,
                              hipStream_t stream) {
  const float* ts = (const float*)d_in[0];
  const float* y0 = (const float*)d_in[1];
  const float* W0 = (const float*)d_in[2];
  const float* b0 = (const float*)d_in[3];
  const float* W1 = (const float*)d_in[4];
  const float* b1 = (const float*)d_in[5];
  const float* W2 = (const float*)d_in[6];
  const float* b2 = (const float*)d_in[7];
  // ws: [0,640K) fp16 weights | 655360: flags (4KB) | 663552: k-partials (3MB)
  f16* wsh = (f16*)d_ws;
  unsigned int* flags = (unsigned int*)((char*)d_ws + 655360);
  float* partials = (float*)((char*)d_ws + 663552);

  cvt_kernel<<<640, 512, 0, stream>>>(W0, W1, W2, wsh);
  hipMemsetAsync(flags, 0, 4096, stream);
  ode_kernel<<<NGRP * NCU, NTHREADS, 0, stream>>>(ts, y0, b0, b1, b2,
                                                  wsh, wsh + 32768, wsh + 294912,
                                                  (float*)d_out, partials, flags);
}

// Round 11
// 1738.924 us; speedup vs baseline: 2.5362x; 2.0593x over previous
//
#include <hip/hip_runtime.h>
#include <stdint.h>

typedef _Float16 f16;
typedef __attribute__((ext_vector_type(8))) _Float16 f16x8;
typedef __attribute__((ext_vector_type(4))) float f32x4;

#define BD 64      // state dim D
#define HW 512     // hidden width W
#define TT 16      // time points T
#define BR 16      // batch rows per group
#define NTHREADS 512
#define NGRP 32    // batch groups (512/16)
#define NCU 4      // CUs per group (W1 split 4 ways, 128 KB LDS-resident each)

// lgkm-only barrier: LDS producer->consumer, no vmcnt drain
#define LBAR() asm volatile("s_waitcnt lgkmcnt(0)\n\ts_barrier" ::: "memory")
#define VM_DRAIN() asm volatile("s_waitcnt vmcnt(0)" ::: "memory")

// Tsit5 coefficients
constexpr float cA21 = 0.161f;
constexpr float cA31 = -0.008480655492356989f, cA32 = 0.335480655492357f;
constexpr float cA41 = 2.8971530571054935f, cA42 = -6.359448489975075f, cA43 = 4.3622954328695815f;
constexpr float cA51 = 5.325864828439257f, cA52 = -11.748883564062828f, cA53 = 7.4955393428898365f, cA54 = -0.09249506636175525f;
constexpr float cA61 = 5.86145544294642f, cA62 = -12.92096931784711f, cA63 = 8.159367898576159f, cA64 = -0.071584973281401f, cA65 = -0.028269050394068383f;
constexpr float cB1 = 0.09646076681806523f, cB2 = 0.01f, cB3 = 0.4798896504144996f;
constexpr float cB4 = 1.379008574103742f, cB5 = -3.290069515436081f, cB6 = 2.324710524099774f;

__device__ __forceinline__ float softplus_f(float x) {
  return fmaxf(x, 0.0f) + __logf(1.0f + __expf(-fabsf(x)));
}

// convert W0 [512,64], W1 [512,512], W2 [64,512] (row-major f32) to fp16 in ws
__global__ void cvt_kernel(const float* __restrict__ w0,
                           const float* __restrict__ w1,
                           const float* __restrict__ w2,
                           f16* __restrict__ wsh) {
  int i = blockIdx.x * 512 + threadIdx.x;
  if (i < 32768) wsh[i] = (f16)w0[i];
  else if (i < 294912) wsh[i] = (f16)w1[i - 32768];
  else if (i < 327680) wsh[i] = (f16)w2[i - 294912];
}

__global__ __launch_bounds__(NTHREADS)
void ode_kernel(const float* __restrict__ ts,
                const float* __restrict__ y0,
                const float* __restrict__ b0,
                const float* __restrict__ b1,
                const float* __restrict__ b2,
                const f16* __restrict__ W0h,
                const f16* __restrict__ W1h,
                const f16* __restrict__ W2h,
                float* __restrict__ out,
                float* partials,
                unsigned int* flags) {
  // resident swizzled W1 slice: 128 rows x 512 cols fp16 = 131072 B
  __shared__ __align__(16) f16 w1s[128 * HW];
  __shared__ __align__(16) f16 h0buf[BR][HW + 8];
  __shared__ __align__(16) f16 h1buf[BR][128 + 8];
  __shared__ __align__(16) f16 atile[BR][BD + 8];
  __shared__ float hsteps[TT - 1];

  const int tid  = threadIdx.x;
  const int wave = tid >> 6;
  const int lane = tid & 63;
  const int m = lane & 15;   // MFMA col index
  const int g = lane >> 4;   // lane group 0..3
  const int b = blockIdx.x;
  const int grp = b & 31;    // batch group; teammates {grp, grp+32, +64, +96}
  const int cuj = b >> 5;    // which quarter of W1/h1/K this CU owns
  const int row0 = grp * BR;
  const int cbase = wave * 64;  // layer-1 output-col base
  const int ntile = wave & 3;   // layer-3 output col tile (waves 0-3 only)
  const int r0 = tid >> 6, d = tid & 63;   // per-thread output elems (r0,d),(r0+8,d)

  // ---- loop-invariant registers ----
  f16x8 w0r[2][4];
#pragma unroll
  for (int kt = 0; kt < 2; ++kt)
#pragma unroll
    for (int nt = 0; nt < 4; ++nt)
      w0r[kt][nt] = *(const f16x8*)&W0h[(cbase + nt * 16 + m) * BD + kt * 32 + g * 8];
  f16x8 w2r[4];  // W2 K-slice [cuj*128, +128) for out tile ntile
#pragma unroll
  for (int kt = 0; kt < 4; ++kt)
    w2r[kt] = *(const f16x8*)&W2h[(ntile * 16 + m) * HW + cuj * 128 + kt * 32 + g * 8];
  float bias0[4];
#pragma unroll
  for (int nt = 0; nt < 4; ++nt) bias0[nt] = b0[cbase + nt * 16 + m];
  // L2 consolidated onto waves 0-3 (2 out-tiles each, 32 cols); per-tile bias
  float bias1v[2] = {0.f, 0.f};
  if (wave < 4) {
#pragma unroll
    for (int tt = 0; tt < 2; ++tt)
      bias1v[tt] = b1[cuj * 128 + (wave * 2 + tt) * 16 + m];
  }
  const float b2d = b2[d];

  // ---- y state in registers ----
  float yreg0 = y0[(row0 + r0) * BD + d];
  float yreg1 = y0[(row0 + r0 + 8) * BD + d];
  atile[r0][d] = (f16)yreg0;
  atile[r0 + 8][d] = (f16)yreg1;
  if (cuj == 0) {
    out[(row0 + r0) * (TT * BD) + d] = yreg0;
    out[(row0 + r0 + 8) * (TT * BD) + d] = yreg1;
  }
  if (tid < TT - 1) hsteps[tid] = (ts[tid + 1] - ts[tid]) * 0.25f;

  // ---- stage resident W1 slice into LDS, XOR-swizzled: byte ^= (row&7)<<4 ----
  for (int idx = tid; idx < 128 * 64; idx += NTHREADS) {
    const int row = idx >> 6, ch = idx & 63;           // ch = 16B chunk (8 f16)
    const f16x8 v = *(const f16x8*)&W1h[(size_t)(cuj * 128 + row) * HW + ch * 8];
    *(f16x8*)((char*)w1s + row * 1024 + ((ch * 16) ^ ((row & 7) << 4))) = v;
  }
  LBAR();

  const int rsw = (m & 7) << 4;   // read-side swizzle ((tile*16+m)&7 == m&7)

  int fstep = 0;
  unsigned int* const flagp = &flags[grp * 32];   // one line per group (R4 layout)

  // one MLP eval of f(atile); k distributed into (KA,KB) on every CU
  auto feval = [&](int st, float& KA, float& KB) {
    // ---- layer 1: full h0 output-split across 8 waves, W0 in regs (R4 verbatim)
    {
      f32x4 acc[4] = {{0,0,0,0},{0,0,0,0},{0,0,0,0},{0,0,0,0}};
#pragma unroll
      for (int kt = 0; kt < 2; ++kt) {
        const f16x8 a = *(const f16x8*)&atile[m][kt * 32 + g * 8];
#pragma unroll
        for (int nt = 0; nt < 4; ++nt)
          acc[nt] = __builtin_amdgcn_mfma_f32_16x16x32_f16(a, w0r[kt][nt], acc[nt], 0, 0, 0);
      }
#pragma unroll
      for (int nt = 0; nt < 4; ++nt) {
        const int n = cbase + nt * 16 + m;
#pragma unroll
        for (int j = 0; j < 4; ++j)
          h0buf[g * 4 + j][n] = (f16)softplus_f(acc[nt][j] + bias0[nt]);
      }
    }
    LBAR();
    // ---- layer 2 (consolidated): waves 0-3 compute 32 cols each (2 out-tiles),
    // one shared A-read per kt (A-reads 128 -> 64, all 4 SIMDs busy)
    if (wave < 4) {
      f32x4 acc[2] = {{0,0,0,0},{0,0,0,0}};
#pragma unroll
      for (int kt = 0; kt < 16; ++kt) {
        const f16x8 a = *(const f16x8*)&h0buf[m][kt * 32 + g * 8];
#pragma unroll
        for (int tt = 0; tt < 2; ++tt) {
          const char* wb = (const char*)w1s + ((wave * 2 + tt) * 16 + m) * 1024;
          const f16x8 bb = *(const f16x8*)(wb + ((kt * 64 + g * 16) ^ rsw));
          acc[tt] = __builtin_amdgcn_mfma_f32_16x16x32_f16(a, bb, acc[tt], 0, 0, 0);
        }
      }
#pragma unroll
      for (int tt = 0; tt < 2; ++tt) {
#pragma unroll
        for (int j = 0; j < 4; ++j)
          h1buf[g * 4 + j][(wave * 2 + tt) * 16 + m] =
              (f16)softplus_f(acc[tt][j] + bias1v[tt]);
      }
    }
    LBAR();
    // ---- layer 3: split-K partial (local K=128); waves 0-3 only
    if (wave < 4) {
      f32x4 acc3 = {0, 0, 0, 0};
#pragma unroll
      for (int kt = 0; kt < 4; ++kt) {
        const f16x8 a = *(const f16x8*)&h1buf[m][kt * 32 + g * 8];
        acc3 = __builtin_amdgcn_mfma_f32_16x16x32_f16(a, w2r[kt], acc3, 0, 0, 0);
      }
      float* const pb = partials + ((size_t)(grp * 6 + st) * 4 + cuj) * 1024;
#pragma unroll
      for (int j = 0; j < 4; ++j)
        __hip_atomic_store(&pb[(g * 4 + j) * 64 + ntile * 16 + m], acc3[j],
                           __ATOMIC_RELAXED, __HIP_MEMORY_SCOPE_AGENT);
    }
    VM_DRAIN();          // own partial stores at coherence point
    LBAR();              // all waves of this block drained
    ++fstep;
    if (tid == 0) {
      __hip_atomic_fetch_add(flagp, 1u, __ATOMIC_RELEASE, __HIP_MEMORY_SCOPE_AGENT);
      const unsigned int tgt = 4u * (unsigned int)fstep;
      while (__hip_atomic_load(flagp, __ATOMIC_ACQUIRE, __HIP_MEMORY_SCOPE_AGENT) < tgt)
        __builtin_amdgcn_s_sleep(1);
    }
    __syncthreads();
    // gather: k[tid], k[tid+512] = sum of 4 CU partials (+ bias); idx=tid (coalesced)
    const float* const q = partials + (size_t)(grp * 6 + st) * 4096;
    float s0 = 0.f, s1 = 0.f;
#pragma unroll
    for (int c = 0; c < 4; ++c) {
      s0 += __hip_atomic_load(q + c * 1024 + tid,       __ATOMIC_RELAXED, __HIP_MEMORY_SCOPE_AGENT);
      s1 += __hip_atomic_load(q + c * 1024 + tid + 512, __ATOMIC_RELAXED, __HIP_MEMORY_SCOPE_AGENT);
    }
    KA = s0 + b2d;
    KB = s1 + b2d;
  };

  float k1a, k1b, k2a, k2b, k3a, k3b, k4a, k4b, k5a, k5b, k6a, k6b;

#define PUT_ATILE(E0, E1) \
  atile[r0][d] = (f16)(E0); atile[r0 + 8][d] = (f16)(E1); LBAR();

  for (int t = 0; t < TT - 1; ++t) {
    const float h = hsteps[t];
    for (int s = 0; s < 4; ++s) {
      feval(0, k1a, k1b);
      PUT_ATILE(yreg0 + h * (cA21 * k1a), yreg1 + h * (cA21 * k1b))
      feval(1, k2a, k2b);
      PUT_ATILE(yreg0 + h * (cA31 * k1a + cA32 * k2a),
                yreg1 + h * (cA31 * k1b + cA32 * k2b))
      feval(2, k3a, k3b);
      PUT_ATILE(yreg0 + h * (cA41 * k1a + cA42 * k2a + cA43 * k3a),
                yreg1 + h * (cA41 * k1b + cA42 * k2b + cA43 * k3b))
      feval(3, k4a, k4b);
      PUT_ATILE(yreg0 + h * (cA51 * k1a + cA52 * k2a + cA53 * k3a + cA54 * k4a),
                yreg1 + h * (cA51 * k1b + cA52 * k2b + cA53 * k3b + cA54 * k4b))
      feval(4, k5a, k5b);
      PUT_ATILE(yreg0 + h * (cA61 * k1a + cA62 * k2a + cA63 * k3a + cA64 * k4a + cA65 * k5a),
                yreg1 + h * (cA61 * k1b + cA62 * k2b + cA63 * k3b + cA64 * k4b + cA65 * k5b))
      feval(5, k6a, k6b);
      yreg0 += h * (cB1 * k1a + cB2 * k2a + cB3 * k3a + cB4 * k4a + cB5 * k5a + cB6 * k6a);
      yreg1 += h * (cB1 * k1b + cB2 * k2b + cB3 * k3b + cB4 * k4b + cB5 * k5b + cB6 * k6b);
      PUT_ATILE(yreg0, yreg1)
    }
    if (cuj == 0) {
      out[(row0 + r0) * (TT * BD) + (t + 1) * BD + d] = yreg0;
      out[(row0 + r0 + 8) * (TT * BD) + (t + 1) * BD + d] = yreg1;
    }
  }
#undef PUT_ATILE
}

extern "C" void kernel_launch(void* const* d_in, const int* in_sizes, int n_in,
                              void* d_out, int out_size, void* d_ws, size_t ws_size,
                              hipStream_t stream) {
  const float* ts = (const float*)d_in[0];
  const float* y0 = (const float*)d_in[1];
  const float* W0 = (const float*)d_in[2];
  const float* b0 = (const float*)d_in[3];
  const float* W1 = (const float*)d_in[4];
  const float* b1 = (const float*)d_in[5];
  const float* W2 = (const float*)d_in[6];
  const float* b2 = (const float*)d_in[7];
  // ws: [0,640K) fp16 weights | 655360: flags (4KB) | 663552: k-partials (3MB)
  f16* wsh = (f16*)d_ws;
  unsigned int* flags = (unsigned int*)((char*)d_ws + 655360);
  float* partials = (float*)((char*)d_ws + 663552);

  cvt_kernel<<<640, 512, 0, stream>>>(W0, W1, W2, wsh);
  hipMemsetAsync(flags, 0, 4096, stream);
  ode_kernel<<<NGRP * NCU, NTHREADS, 0, stream>>>(ts, y0, b0, b1, b2,
                                                  wsh, wsh + 32768, wsh + 294912,
                                                  (float*)d_out, partials, flags);
}